// Round 5
// baseline (150.426 us; speedup 1.0000x reference)
//
#include <hip/hip_runtime.h>
#include <hip/hip_bf16.h>

// Problem constants (fixed by setup_inputs)
#define NB   8      // batch
#define DK   256    // dk (4 mixtures x 64)
#define LL   2048   // Lq == Lk
#define DV   256    // dv
#define NMIX 4
#define EP   136    // E-buffer pitch in shorts (128 + 8 pad)

typedef __attribute__((ext_vector_type(8))) short bf16x8;
typedef __attribute__((ext_vector_type(4))) float f32x4;

__device__ __forceinline__ unsigned short f2bf(float x) {
    unsigned int u = __float_as_uint(x);
    return (unsigned short)((u + 0x7FFFu + ((u >> 16) & 1u)) >> 16);  // RNE
}
__device__ __forceinline__ float bf2f(unsigned short u) {
    return __uint_as_float(((unsigned int)u) << 16);
}

// ---------------------------------------------------------------------------
// Pack K and V into exact MFMA fragment order (contiguous 1KB per wave-frag).
// Kp[((b*128+kt16)*8+cc)*64 + lane][i] = bf16(K[b][cc*32+lg*8+i][kt16*16+lc])
//   (B-operand of S = mfma(Q, K): B[ch=lg*8+i][kcol=lc])
// Vp[((b*64+kt32)*16+vj)*64 + lane][i] = bf16(V[b][vj*16+lc][kt32*32+lg*8+i])
//   (B-operand of O = mfma(E, V): B[k=lg*8+i][vcol=lc])
__global__ void pack_kv(const float* __restrict__ key,
                        const float* __restrict__ value,
                        unsigned short* __restrict__ Kp,
                        unsigned short* __restrict__ Vp) {
    const int gid0 = blockIdx.x * 256 + threadIdx.x;
    if (blockIdx.x < 2048) {
        const int gid = gid0;                 // 0 .. 524287
        const int lane = gid & 63;
        const int cc   = (gid >> 6) & 7;      // 32-ch chunk
        const int kt   = (gid >> 9) & 127;    // 16-k tile
        const int b    = gid >> 16;
        const int lg = lane >> 4, lc = lane & 15;
        const float* src = key + ((size_t)b * DK + cc * 32 + lg * 8) * LL + kt * 16 + lc;
        bf16x8 o;
        #pragma unroll
        for (int i = 0; i < 8; ++i) o[i] = (short)f2bf(src[(size_t)i * LL]);
        *reinterpret_cast<bf16x8*>(Kp + (size_t)gid * 8) = o;
    } else {
        const int gid = gid0 - 2048 * 256;    // 0 .. 524287
        const int lane = gid & 63;
        const int vj   = (gid >> 6) & 15;
        const int kt   = (gid >> 10) & 63;    // 32-k tile
        const int b    = gid >> 16;
        const int lg = lane >> 4, lc = lane & 15;
        const float* src = value + ((size_t)b * DV + vj * 16 + lc) * LL + kt * 32 + lg * 8;
        float4 v0 = *reinterpret_cast<const float4*>(src);
        float4 v1 = *reinterpret_cast<const float4*>(src + 4);
        bf16x8 o;
        o[0] = (short)f2bf(v0.x); o[1] = (short)f2bf(v0.y);
        o[2] = (short)f2bf(v0.z); o[3] = (short)f2bf(v0.w);
        o[4] = (short)f2bf(v1.x); o[5] = (short)f2bf(v1.y);
        o[6] = (short)f2bf(v1.z); o[7] = (short)f2bf(v1.w);
        *reinterpret_cast<bf16x8*>(Vp + (size_t)gid * 8) = o;
    }
}

// avg_query: one block per (b*DK + d) row, mean over LL
__global__ void avg_k(const float* __restrict__ q, float* __restrict__ avg) {
    const int row = blockIdx.x;
    const float* p = q + (size_t)row * LL;
    float s = 0.f;
    for (int i = threadIdx.x; i < LL; i += 256) s += p[i];
    #pragma unroll
    for (int off = 32; off >= 1; off >>= 1) s += __shfl_down(s, off);
    __shared__ float ps[4];
    if ((threadIdx.x & 63) == 0) ps[threadIdx.x >> 6] = s;
    __syncthreads();
    if (threadIdx.x == 0)
        avg[row] = (ps[0] + ps[1] + ps[2] + ps[3]) * (1.0f / LL);
}

// pi = softmax_m( w[m,:] . avg[b,:] ) ; one wave per b
__global__ void pi_k(const float* __restrict__ wgt, const float* __restrict__ avg,
                     float* __restrict__ piOut) {
    const int b = blockIdx.x;
    const int l = threadIdx.x;   // 0..63
    float part[NMIX] = {0.f, 0.f, 0.f, 0.f};
    for (int d = l; d < DK; d += 64) {
        float a = avg[b * DK + d];
        #pragma unroll
        for (int m = 0; m < NMIX; ++m) part[m] += wgt[m * DK + d] * a;
    }
    #pragma unroll
    for (int off = 1; off < 64; off <<= 1) {
        #pragma unroll
        for (int m = 0; m < NMIX; ++m) part[m] += __shfl_xor(part[m], off);
    }
    float mx = fmaxf(fmaxf(part[0], part[1]), fmaxf(part[2], part[3]));
    float e0 = __expf(part[0] - mx), e1 = __expf(part[1] - mx);
    float e2 = __expf(part[2] - mx), e3 = __expf(part[3] - mx);
    float z = e0 + e1 + e2 + e3;
    float mine = (l == 0) ? e0 : (l == 1) ? e1 : (l == 2) ? e2 : e3;
    if (l < NMIX) piOut[b * NMIX + l] = mine / z;
}

// ---------------------------------------------------------------------------
// Q A-fragment hoist from RAW f32 query (amortized over the whole k sweep).
// A[row=q=lc][ch=lg*8+i]; qf[qt][m][c].
__device__ __forceinline__ void hoist_q(const float* __restrict__ query,
                                        int b, int qb, int lg, int lc,
                                        bf16x8 qf[2][4][2]) {
    #pragma unroll
    for (int qt = 0; qt < 2; ++qt)
        #pragma unroll
        for (int m = 0; m < 4; ++m)
            #pragma unroll
            for (int c = 0; c < 2; ++c) {
                const float* src = query + ((size_t)b * DK + m * 64 + c * 32 + lg * 8) * LL
                                   + qb + qt * 16 + lc;
                bf16x8 f;
                #pragma unroll
                for (int i = 0; i < 8; ++i) f[i] = (short)f2bf(src[(size_t)i * LL]);
                qf[qt][m][c] = f;
            }
}

// ---------------------------------------------------------------------------
// Z pre-pass: Zh[kh][b][q][m] = sum_{k in half} exp2(S*ES).
// grid 1024 = b(8) x qt64(64, 32 q-rows) x kh(2). 4 waves k-split the half.
__launch_bounds__(256, 4)
__global__ void zsum_k(const float* __restrict__ query,
                       const unsigned short* __restrict__ Kp,
                       float* __restrict__ Zh) {
    const int bid = blockIdx.x;
    const int b    = bid & 7;             // XCD affinity
    const int qt64 = (bid >> 3) & 63;
    const int kh   = bid >> 9;
    const int qb   = qt64 * 32;
    const int tid  = threadIdx.x;
    const int w = tid >> 6, lane = tid & 63, lg = lane >> 4, lc = lane & 15;

    bf16x8 qf[2][4][2];
    hoist_q(query, b, qb, lg, lc, qf);

    const unsigned short* kpB = Kp + (size_t)b * 128 * 8 * 512;
    const float ES = 0.09016844005555896f;   // log2(e)/16

    float zs[2][4][4];
    #pragma unroll
    for (int qt = 0; qt < 2; ++qt)
        #pragma unroll
        for (int m = 0; m < 4; ++m)
            #pragma unroll
            for (int r = 0; r < 4; ++r) zs[qt][m][r] = 0.f;

    for (int t = 0; t < 16; ++t) {
        const int ktile = kh * 64 + w * 16 + t;
        const unsigned short* kp = kpB + (size_t)ktile * 8 * 512 + lane * 8;
        #pragma unroll
        for (int m = 0; m < 4; ++m) {
            bf16x8 k0 = *reinterpret_cast<const bf16x8*>(kp + (m * 2 + 0) * 512);
            bf16x8 k1 = *reinterpret_cast<const bf16x8*>(kp + (m * 2 + 1) * 512);
            #pragma unroll
            for (int qt = 0; qt < 2; ++qt) {
                f32x4 s = {0.f, 0.f, 0.f, 0.f};
                s = __builtin_amdgcn_mfma_f32_16x16x32_bf16(qf[qt][m][0], k0, s, 0, 0, 0);
                s = __builtin_amdgcn_mfma_f32_16x16x32_bf16(qf[qt][m][1], k1, s, 0, 0, 0);
                #pragma unroll
                for (int r = 0; r < 4; ++r)
                    zs[qt][m][r] += __builtin_amdgcn_exp2f(s[r] * ES);
            }
        }
    }
    // reduce over the 16 k-columns (lc)
    #pragma unroll
    for (int qt = 0; qt < 2; ++qt)
        #pragma unroll
        for (int m = 0; m < 4; ++m)
            #pragma unroll
            for (int r = 0; r < 4; ++r) {
                float v = zs[qt][m][r];
                v += __shfl_xor(v, 1);
                v += __shfl_xor(v, 2);
                v += __shfl_xor(v, 4);
                v += __shfl_xor(v, 8);
                zs[qt][m][r] = v;
            }
    __shared__ float Zp[4][2][4][4][4];   // [w][qt][lg][m][r]
    if (lc == 0) {
        #pragma unroll
        for (int qt = 0; qt < 2; ++qt)
            #pragma unroll
            for (int m = 0; m < 4; ++m)
                #pragma unroll
                for (int r = 0; r < 4; ++r) Zp[w][qt][lg][m][r] = zs[qt][m][r];
    }
    __syncthreads();
    if (tid < 128) {
        const int q = tid >> 2, m = tid & 3;
        const int qt = q >> 4, g = (q >> 2) & 3, r = q & 3;
        float z = Zp[0][qt][g][m][r] + Zp[1][qt][g][m][r]
                + Zp[2][qt][g][m][r] + Zp[3][qt][g][m][r];
        Zh[(((size_t)kh * NB + b) * LL + qb + q) * NMIX + m] = z;
    }
}

// ---------------------------------------------------------------------------
// Main kernel: attn + O. grid 512 = b(8) x qt64(64, 32 q-rows); 256 thr / 4 waves.
// Per 128-k window j: wave v computes QK for its 32-k slice (standard
// orientation, Kp contiguous loads), writes combined-E bf16 to LDS; barrier;
// coalesced attn store pass from E; PV = mfma(E-frag, Vp-frag) with each wave
// owning a 4-vj quarter (Kp and Vp each read exactly once per block).
__launch_bounds__(256, 2)
__global__ void mos_attn(const float* __restrict__ query,
                         const unsigned short* __restrict__ Kp,
                         const unsigned short* __restrict__ Vp,
                         const float* __restrict__ Zh,
                         const float* __restrict__ piAll,
                         float* __restrict__ out,
                         float* __restrict__ attn) {
    const int bid = blockIdx.x;
    const int b    = bid & 7;             // XCD affinity
    const int qt64 = bid >> 3;            // 0..63
    const int qb   = qt64 * 32;
    const int tid  = threadIdx.x;
    const int v = tid >> 6, lane = tid & 63, lg = lane >> 4, lc = lane & 15;

    __shared__ __align__(16) unsigned short E[32 * EP];

    bf16x8 qf[2][4][2];
    hoist_q(query, b, qb, lg, lc, qf);

    // C[qt][m][r] = log2( pi_m / Z[q] ),  q = qb + qt*16 + lg*4 + r
    float C[2][4][4];
    #pragma unroll
    for (int qt = 0; qt < 2; ++qt)
        #pragma unroll
        for (int r = 0; r < 4; ++r) {
            const int q = qb + qt * 16 + lg * 4 + r;
            #pragma unroll
            for (int m = 0; m < 4; ++m) {
                float z = Zh[((size_t)b * LL + q) * NMIX + m]
                        + Zh[((size_t)(NB + b) * LL + q) * NMIX + m];
                C[qt][m][r] = __log2f(piAll[b * NMIX + m] / z);
            }
        }

    const unsigned short* kpB = Kp + (size_t)b * 128 * 8 * 512;
    const unsigned short* vpB = Vp + (size_t)b * 64 * 16 * 512;
    const float ES = 0.09016844005555896f;

    f32x4 oacc[2][4];
    #pragma unroll
    for (int qt = 0; qt < 2; ++qt)
        #pragma unroll
        for (int vj = 0; vj < 4; ++vj) oacc[qt][vj] = (f32x4){0.f, 0.f, 0.f, 0.f};

    for (int j = 0; j < 16; ++j) {
        // ---- QK for this wave's 32-k slice (2 x 16-k tiles) ----
        #pragma unroll
        for (int kt = 0; kt < 2; ++kt) {
            const int ktile = j * 8 + v * 2 + kt;
            const unsigned short* kp = kpB + (size_t)ktile * 8 * 512 + lane * 8;
            float av[2][4];
            #pragma unroll
            for (int qt = 0; qt < 2; ++qt)
                #pragma unroll
                for (int r = 0; r < 4; ++r) av[qt][r] = 0.f;
            #pragma unroll
            for (int m = 0; m < 4; ++m) {
                bf16x8 k0 = *reinterpret_cast<const bf16x8*>(kp + (m * 2 + 0) * 512);
                bf16x8 k1 = *reinterpret_cast<const bf16x8*>(kp + (m * 2 + 1) * 512);
                #pragma unroll
                for (int qt = 0; qt < 2; ++qt) {
                    f32x4 s = {0.f, 0.f, 0.f, 0.f};
                    s = __builtin_amdgcn_mfma_f32_16x16x32_bf16(qf[qt][m][0], k0, s, 0, 0, 0);
                    s = __builtin_amdgcn_mfma_f32_16x16x32_bf16(qf[qt][m][1], k1, s, 0, 0, 0);
                    #pragma unroll
                    for (int r = 0; r < 4; ++r)
                        av[qt][r] += __builtin_amdgcn_exp2f(fmaf(s[r], ES, C[qt][m][r]));
                }
            }
            // write combined-E: row = qt*16 + lg*4 + r, col = v*32 + kt*16 + lc
            #pragma unroll
            for (int qt = 0; qt < 2; ++qt)
                #pragma unroll
                for (int r = 0; r < 4; ++r)
                    E[(qt * 16 + lg * 4 + r) * EP + v * 32 + kt * 16 + lc] =
                        f2bf(av[qt][r]);
        }
        __syncthreads();

        // ---- coalesced attn store pass (512B contiguous per row) ----
        {
            const int row = tid >> 3, kc = (tid & 7) * 16;
            bf16x8 e0 = *reinterpret_cast<const bf16x8*>(&E[row * EP + kc]);
            bf16x8 e1 = *reinterpret_cast<const bf16x8*>(&E[row * EP + kc + 8]);
            float* ap = attn + ((size_t)b * LL + qb + row) * LL + j * 128 + kc;
            f32x4 f0, f1, f2, f3;
            #pragma unroll
            for (int i = 0; i < 4; ++i) {
                f0[i] = bf2f((unsigned short)e0[i]);
                f1[i] = bf2f((unsigned short)e0[i + 4]);
                f2[i] = bf2f((unsigned short)e1[i]);
                f3[i] = bf2f((unsigned short)e1[i + 4]);
            }
            *reinterpret_cast<f32x4*>(ap + 0)  = f0;
            *reinterpret_cast<f32x4*>(ap + 4)  = f1;
            *reinterpret_cast<f32x4*>(ap + 8)  = f2;
            *reinterpret_cast<f32x4*>(ap + 12) = f3;
        }

        // ---- PV: wave owns vj quarter v*4..v*4+3; k = full 128 window ----
        #pragma unroll
        for (int kc = 0; kc < 4; ++kc) {
            bf16x8 ea0 = *reinterpret_cast<const bf16x8*>(&E[lc * EP + kc * 32 + lg * 8]);
            bf16x8 ea1 = *reinterpret_cast<const bf16x8*>(&E[(16 + lc) * EP + kc * 32 + lg * 8]);
            const unsigned short* vpt = vpB + ((size_t)(j * 4 + kc) * 16 + v * 4) * 512 + lane * 8;
            #pragma unroll
            for (int vj = 0; vj < 4; ++vj) {
                bf16x8 vf = *reinterpret_cast<const bf16x8*>(vpt + vj * 512);
                oacc[0][vj] = __builtin_amdgcn_mfma_f32_16x16x32_bf16(ea0, vf, oacc[0][vj], 0, 0, 0);
                oacc[1][vj] = __builtin_amdgcn_mfma_f32_16x16x32_bf16(ea1, vf, oacc[1][vj], 0, 0, 0);
            }
        }
        __syncthreads();
    }

    // out: q = qb + qt*16 + lg*4 + d ; vcol = (v*4+vj)*16 + lc
    #pragma unroll
    for (int qt = 0; qt < 2; ++qt)
        #pragma unroll
        for (int vj = 0; vj < 4; ++vj)
            #pragma unroll
            for (int d = 0; d < 4; ++d)
                out[((size_t)b * LL + qb + qt * 16 + lg * 4 + d) * DV
                    + (v * 4 + vj) * 16 + lc] = oacc[qt][vj][d];
}

// ---------------------------------------------------------------------------
extern "C" void kernel_launch(void* const* d_in, const int* in_sizes, int n_in,
                              void* d_out, int out_size, void* d_ws, size_t ws_size,
                              hipStream_t stream) {
    const float* query   = (const float*)d_in[0];   // (8, 256, 2048)
    const float* key     = (const float*)d_in[1];   // (8, 256, 2048)
    const float* value   = (const float*)d_in[2];   // (8, 256, 2048)
    const float* weights = (const float*)d_in[3];   // (4, 256)

    float* out  = (float*)d_out;                    // (8, 2048, 256)
    float* attn = out + (size_t)NB * LL * DV;       // (8, 2048, 2048)

    // workspace (~17.3 MB)
    char* ws = (char*)d_ws;
    float* avg = (float*)ws;                              // 8KB
    float* pi  = (float*)(ws + 8192);                     // 32B
    float* Zh  = (float*)(ws + 12288);                    // 512KB
    unsigned short* Kp = (unsigned short*)(ws + 536576);  // 8.4MB packed K frags
    unsigned short* Vp = Kp + (size_t)NB * LL * DK;       // 8.4MB packed V frags

    avg_k<<<NB * DK, 256, 0, stream>>>(query, avg);
    pi_k<<<NB, 64, 0, stream>>>(weights, avg, pi);
    pack_kv<<<4096, 256, 0, stream>>>(key, value, Kp, Vp);
    zsum_k<<<1024, 256, 0, stream>>>(query, Kp, Zh);
    mos_attn<<<512, 256, 0, stream>>>(query, Kp, Vp, Zh, pi, out, attn);
}

// Round 6
// 137.235 us; speedup vs baseline: 1.0961x; 1.0961x over previous
//
#include <hip/hip_runtime.h>
#include <hip/hip_bf16.h>

// Problem constants (fixed by setup_inputs)
#define NB   8      // batch
#define DK   256    // dk (4 mixtures x 64)
#define LL   2048   // Lq == Lk
#define DV   256    // dv
#define NMIX 4
#define EP2  132    // E pitch in shorts: 66 dwords/row, 66%32=2 -> write banks spread

typedef __attribute__((ext_vector_type(8))) short bf16x8;
typedef __attribute__((ext_vector_type(4))) float f32x4;

__device__ __forceinline__ unsigned short f2bf(float x) {
    unsigned int u = __float_as_uint(x);
    return (unsigned short)((u + 0x7FFFu + ((u >> 16) & 1u)) >> 16);  // RNE
}
__device__ __forceinline__ float bf2f(unsigned short u) {
    return __uint_as_float(((unsigned int)u) << 16);
}

// ---------------------------------------------------------------------------
// Pack K and V into exact MFMA fragment order (contiguous 1KB per wave-frag).
// Kp[((b*128+kt16)*8+cc)*64 + lane][i] = bf16(K[b][cc*32+lg*8+i][kt16*16+lc])
// Vp[((b*64+kt32)*16+vj)*64 + lane][i] = bf16(V[b][vj*16+lc][kt32*32+lg*8+i])
__global__ void pack_kv(const float* __restrict__ key,
                        const float* __restrict__ value,
                        unsigned short* __restrict__ Kp,
                        unsigned short* __restrict__ Vp) {
    const int gid0 = blockIdx.x * 256 + threadIdx.x;
    if (blockIdx.x < 2048) {
        const int gid = gid0;                 // 0 .. 524287
        const int lane = gid & 63;
        const int cc   = (gid >> 6) & 7;      // 32-ch chunk
        const int kt   = (gid >> 9) & 127;    // 16-k tile
        const int b    = gid >> 16;
        const int lg = lane >> 4, lc = lane & 15;
        const float* src = key + ((size_t)b * DK + cc * 32 + lg * 8) * LL + kt * 16 + lc;
        bf16x8 o;
        #pragma unroll
        for (int i = 0; i < 8; ++i) o[i] = (short)f2bf(src[(size_t)i * LL]);
        *reinterpret_cast<bf16x8*>(Kp + (size_t)gid * 8) = o;
    } else {
        const int gid = gid0 - 2048 * 256;    // 0 .. 524287
        const int lane = gid & 63;
        const int vj   = (gid >> 6) & 15;
        const int kt   = (gid >> 10) & 63;    // 32-k tile
        const int b    = gid >> 16;
        const int lg = lane >> 4, lc = lane & 15;
        const float* src = value + ((size_t)b * DV + vj * 16 + lc) * LL + kt * 32 + lg * 8;
        float4 v0 = *reinterpret_cast<const float4*>(src);
        float4 v1 = *reinterpret_cast<const float4*>(src + 4);
        bf16x8 o;
        o[0] = (short)f2bf(v0.x); o[1] = (short)f2bf(v0.y);
        o[2] = (short)f2bf(v0.z); o[3] = (short)f2bf(v0.w);
        o[4] = (short)f2bf(v1.x); o[5] = (short)f2bf(v1.y);
        o[6] = (short)f2bf(v1.z); o[7] = (short)f2bf(v1.w);
        *reinterpret_cast<bf16x8*>(Vp + (size_t)gid * 8) = o;
    }
}

// avg_query: one block per (b*DK + d) row, mean over LL
__global__ void avg_k(const float* __restrict__ q, float* __restrict__ avg) {
    const int row = blockIdx.x;
    const float* p = q + (size_t)row * LL;
    float s = 0.f;
    for (int i = threadIdx.x; i < LL; i += 256) s += p[i];
    #pragma unroll
    for (int off = 32; off >= 1; off >>= 1) s += __shfl_down(s, off);
    __shared__ float ps[4];
    if ((threadIdx.x & 63) == 0) ps[threadIdx.x >> 6] = s;
    __syncthreads();
    if (threadIdx.x == 0)
        avg[row] = (ps[0] + ps[1] + ps[2] + ps[3]) * (1.0f / LL);
}

// pi = softmax_m( w[m,:] . avg[b,:] ) ; one wave per b
__global__ void pi_k(const float* __restrict__ wgt, const float* __restrict__ avg,
                     float* __restrict__ piOut) {
    const int b = blockIdx.x;
    const int l = threadIdx.x;   // 0..63
    float part[NMIX] = {0.f, 0.f, 0.f, 0.f};
    for (int d = l; d < DK; d += 64) {
        float a = avg[b * DK + d];
        #pragma unroll
        for (int m = 0; m < NMIX; ++m) part[m] += wgt[m * DK + d] * a;
    }
    #pragma unroll
    for (int off = 1; off < 64; off <<= 1) {
        #pragma unroll
        for (int m = 0; m < NMIX; ++m) part[m] += __shfl_xor(part[m], off);
    }
    float mx = fmaxf(fmaxf(part[0], part[1]), fmaxf(part[2], part[3]));
    float e0 = __expf(part[0] - mx), e1 = __expf(part[1] - mx);
    float e2 = __expf(part[2] - mx), e3 = __expf(part[3] - mx);
    float z = e0 + e1 + e2 + e3;
    float mine = (l == 0) ? e0 : (l == 1) ? e1 : (l == 2) ? e2 : e3;
    if (l < NMIX) piOut[b * NMIX + l] = mine / z;
}

// ---------------------------------------------------------------------------
// Q A-fragment hoist from RAW f32 query: A[row=q=lc][ch=lg*8+i]; qf[qt][m][c].
__device__ __forceinline__ void hoist_q2(const float* __restrict__ query,
                                         int b, int qrow0, int lg, int lc,
                                         bf16x8 qf[2][4][2]) {
    #pragma unroll
    for (int qt = 0; qt < 2; ++qt)
        #pragma unroll
        for (int m = 0; m < 4; ++m)
            #pragma unroll
            for (int c = 0; c < 2; ++c) {
                const float* src = query + ((size_t)b * DK + m * 64 + c * 32 + lg * 8) * LL
                                   + qrow0 + qt * 16 + lc;
                bf16x8 f;
                #pragma unroll
                for (int i = 0; i < 8; ++i) f[i] = (short)f2bf(src[(size_t)i * LL]);
                qf[qt][m][c] = f;
            }
}

// ---------------------------------------------------------------------------
// Z pre-pass: Zh[kh][b][q][m] = sum_{k in half} exp2(S*ES).
// grid 1024 = b(8) x qt64(64, 32 q-rows) x kh(2). 4 waves k-split the half.
__launch_bounds__(256, 4)
__global__ void zsum_k(const float* __restrict__ query,
                       const unsigned short* __restrict__ Kp,
                       float* __restrict__ Zh) {
    const int bid = blockIdx.x;
    const int b    = bid & 7;             // XCD affinity
    const int qt64 = (bid >> 3) & 63;
    const int kh   = bid >> 9;
    const int qb   = qt64 * 32;
    const int tid  = threadIdx.x;
    const int w = tid >> 6, lane = tid & 63, lg = lane >> 4, lc = lane & 15;

    bf16x8 qf[2][4][2];
    hoist_q2(query, b, qb, lg, lc, qf);

    const unsigned short* kpB = Kp + (size_t)b * 128 * 8 * 512;
    const float ES = 0.09016844005555896f;   // log2(e)/16

    float zs[2][4][4];
    #pragma unroll
    for (int qt = 0; qt < 2; ++qt)
        #pragma unroll
        for (int m = 0; m < 4; ++m)
            #pragma unroll
            for (int r = 0; r < 4; ++r) zs[qt][m][r] = 0.f;

    for (int t = 0; t < 16; ++t) {
        const int ktile = kh * 64 + w * 16 + t;
        const unsigned short* kp = kpB + (size_t)ktile * 8 * 512 + lane * 8;
        #pragma unroll
        for (int m = 0; m < 4; ++m) {
            bf16x8 k0 = *reinterpret_cast<const bf16x8*>(kp + (m * 2 + 0) * 512);
            bf16x8 k1 = *reinterpret_cast<const bf16x8*>(kp + (m * 2 + 1) * 512);
            #pragma unroll
            for (int qt = 0; qt < 2; ++qt) {
                f32x4 s = {0.f, 0.f, 0.f, 0.f};
                s = __builtin_amdgcn_mfma_f32_16x16x32_bf16(qf[qt][m][0], k0, s, 0, 0, 0);
                s = __builtin_amdgcn_mfma_f32_16x16x32_bf16(qf[qt][m][1], k1, s, 0, 0, 0);
                #pragma unroll
                for (int r = 0; r < 4; ++r)
                    zs[qt][m][r] += __builtin_amdgcn_exp2f(s[r] * ES);
            }
        }
    }
    // reduce over the 16 k-columns (lc)
    #pragma unroll
    for (int qt = 0; qt < 2; ++qt)
        #pragma unroll
        for (int m = 0; m < 4; ++m)
            #pragma unroll
            for (int r = 0; r < 4; ++r) {
                float v = zs[qt][m][r];
                v += __shfl_xor(v, 1);
                v += __shfl_xor(v, 2);
                v += __shfl_xor(v, 4);
                v += __shfl_xor(v, 8);
                zs[qt][m][r] = v;
            }
    __shared__ float Zp[4][2][4][4][4];   // [w][qt][lg][m][r]
    if (lc == 0) {
        #pragma unroll
        for (int qt = 0; qt < 2; ++qt)
            #pragma unroll
            for (int m = 0; m < 4; ++m)
                #pragma unroll
                for (int r = 0; r < 4; ++r) Zp[w][qt][lg][m][r] = zs[qt][m][r];
    }
    __syncthreads();
    if (tid < 128) {
        const int q = tid >> 2, m = tid & 3;
        const int qt = q >> 4, g = (q >> 2) & 3, r = q & 3;
        float z = Zp[0][qt][g][m][r] + Zp[1][qt][g][m][r]
                + Zp[2][qt][g][m][r] + Zp[3][qt][g][m][r];
        Zh[(((size_t)kh * NB + b) * LL + qb + q) * NMIX + m] = z;
    }
}

// ---------------------------------------------------------------------------
// Main kernel v6: grid 256 = b(8) x qt(32, 64 q-rows); 1024 threads / 16 waves
// (1 block/CU, 4 waves/SIMD). Per 128-k window j (16 iters, ONE barrier each):
//   QK: wave (wq=w>>2, wk=w&3) computes 16q x 32k from contiguous Kp frags
//       (4 wq-waves hit the same frags ~same-cycle -> L1), combined-softmax E
//       -> double-buffered LDS tile E[2][64][132].
//   barrier.
//   attn store: 1024 threads stream the 64x128 E tile as coalesced f32x4.
//   PV: wave w owns v-tile vj=w: reads E A-frags (all 64 q) from LDS, Vp frags
//       exactly once, accumulates oacc[4 qg].
__launch_bounds__(1024, 4)
__global__ void mos_attn(const float* __restrict__ query,
                         const unsigned short* __restrict__ Kp,
                         const unsigned short* __restrict__ Vp,
                         const float* __restrict__ Zh,
                         const float* __restrict__ piAll,
                         float* __restrict__ out,
                         float* __restrict__ attn) {
    const int bid = blockIdx.x;
    const int b   = bid & 7;             // XCD affinity
    const int qt  = bid >> 3;            // 0..31
    const int qb  = qt * 64;
    const int tid = threadIdx.x;
    const int w = tid >> 6, lane = tid & 63, lg = lane >> 4, lc = lane & 15;
    const int wq = w >> 2, wk = w & 3;

    __shared__ __align__(16) unsigned short E[2][64 * EP2];   // 33.8 KB

    // Q fragments for this wave's 16 q-rows (A[row=q=lc][ch=lg*8+i])
    bf16x8 qf[4][2];
    #pragma unroll
    for (int m = 0; m < 4; ++m)
        #pragma unroll
        for (int c = 0; c < 2; ++c) {
            const float* src = query + ((size_t)b * DK + m * 64 + c * 32 + lg * 8) * LL
                               + qb + wq * 16 + lc;
            bf16x8 f;
            #pragma unroll
            for (int i = 0; i < 8; ++i) f[i] = (short)f2bf(src[(size_t)i * LL]);
            qf[m][c] = f;
        }

    // C[m][r] = log2(pi_m / Z) for q = qb + wq*16 + lg*4 + r
    float C[4][4];
    #pragma unroll
    for (int r = 0; r < 4; ++r) {
        const int q = qb + wq * 16 + lg * 4 + r;
        #pragma unroll
        for (int m = 0; m < 4; ++m) {
            float z = Zh[((size_t)b * LL + q) * NMIX + m]
                    + Zh[((size_t)(NB + b) * LL + q) * NMIX + m];
            C[m][r] = __log2f(piAll[b * NMIX + m] / z);
        }
    }

    const unsigned short* kpB = Kp + (size_t)b * 128 * 8 * 512;
    const unsigned short* vpB = Vp + (size_t)b * 64 * 16 * 512;
    const float ES = 0.09016844005555896f;

    f32x4 oacc[4];
    #pragma unroll
    for (int qg = 0; qg < 4; ++qg) oacc[qg] = (f32x4){0.f, 0.f, 0.f, 0.f};

    // attn streaming pointer for this thread (row = tid>>4, col = (tid&15)*8)
    float* arow = attn + ((size_t)b * LL + qb + (tid >> 4)) * LL + (tid & 15) * 8;

    for (int j = 0; j < 16; ++j) {
        const int buf = j & 1;
        // ---- QK: this wave's 32-k slice (2 x 16-k tiles) ----
        #pragma unroll
        for (int kt = 0; kt < 2; ++kt) {
            const int ktile = j * 8 + wk * 2 + kt;
            const unsigned short* kp = kpB + (size_t)ktile * 8 * 512 + lane * 8;
            float av[4] = {0.f, 0.f, 0.f, 0.f};
            #pragma unroll
            for (int m = 0; m < 4; ++m) {
                bf16x8 k0 = *reinterpret_cast<const bf16x8*>(kp + (m * 2 + 0) * 512);
                bf16x8 k1 = *reinterpret_cast<const bf16x8*>(kp + (m * 2 + 1) * 512);
                f32x4 s = {0.f, 0.f, 0.f, 0.f};
                s = __builtin_amdgcn_mfma_f32_16x16x32_bf16(qf[m][0], k0, s, 0, 0, 0);
                s = __builtin_amdgcn_mfma_f32_16x16x32_bf16(qf[m][1], k1, s, 0, 0, 0);
                #pragma unroll
                for (int r = 0; r < 4; ++r)
                    av[r] += __builtin_amdgcn_exp2f(fmaf(s[r], ES, C[m][r]));
            }
            #pragma unroll
            for (int r = 0; r < 4; ++r)
                E[buf][(wq * 16 + lg * 4 + r) * EP2 + wk * 32 + kt * 16 + lc] =
                    f2bf(av[r]);
        }
        __syncthreads();

        // ---- attn store: coalesced f32x4 from the E tile ----
        {
            bf16x8 e = *reinterpret_cast<const bf16x8*>(
                &E[buf][(tid >> 4) * EP2 + (tid & 15) * 8]);
            f32x4 f0, f1;
            #pragma unroll
            for (int i = 0; i < 4; ++i) {
                f0[i] = bf2f((unsigned short)e[i]);
                f1[i] = bf2f((unsigned short)e[i + 4]);
            }
            *reinterpret_cast<f32x4*>(arow + j * 128)     = f0;
            *reinterpret_cast<f32x4*>(arow + j * 128 + 4) = f1;
        }

        // ---- PV: wave owns v-tile vj = w; k = full 128 window ----
        bf16x8 vf[4];
        #pragma unroll
        for (int kc = 0; kc < 4; ++kc)
            vf[kc] = *reinterpret_cast<const bf16x8*>(
                vpB + ((size_t)(j * 4 + kc) * 16 + w) * 512 + lane * 8);
        #pragma unroll
        for (int kc = 0; kc < 4; ++kc) {
            #pragma unroll
            for (int qg = 0; qg < 4; ++qg) {
                bf16x8 ea = *reinterpret_cast<const bf16x8*>(
                    &E[buf][(qg * 16 + lc) * EP2 + kc * 32 + lg * 8]);
                oacc[qg] = __builtin_amdgcn_mfma_f32_16x16x32_bf16(ea, vf[kc], oacc[qg], 0, 0, 0);
            }
        }
        // no second barrier: next QK writes E[buf^1]; E[buf] rewritten only
        // after the NEXT barrier -> PV/attn reads of E[buf] are safe.
    }

    // out: q = qb + qg*16 + lg*4 + d ; vcol = w*16 + lc
    #pragma unroll
    for (int qg = 0; qg < 4; ++qg)
        #pragma unroll
        for (int d = 0; d < 4; ++d)
            out[((size_t)b * LL + qb + qg * 16 + lg * 4 + d) * DV + w * 16 + lc] =
                oacc[qg][d];
}

// ---------------------------------------------------------------------------
extern "C" void kernel_launch(void* const* d_in, const int* in_sizes, int n_in,
                              void* d_out, int out_size, void* d_ws, size_t ws_size,
                              hipStream_t stream) {
    const float* query   = (const float*)d_in[0];   // (8, 256, 2048)
    const float* key     = (const float*)d_in[1];   // (8, 256, 2048)
    const float* value   = (const float*)d_in[2];   // (8, 256, 2048)
    const float* weights = (const float*)d_in[3];   // (4, 256)

    float* out  = (float*)d_out;                    // (8, 2048, 256)
    float* attn = out + (size_t)NB * LL * DV;       // (8, 2048, 2048)

    // workspace (~17.3 MB)
    char* ws = (char*)d_ws;
    float* avg = (float*)ws;                              // 8KB
    float* pi  = (float*)(ws + 8192);                     // 32B
    float* Zh  = (float*)(ws + 12288);                    // 512KB
    unsigned short* Kp = (unsigned short*)(ws + 536576);  // 8.4MB packed K frags
    unsigned short* Vp = Kp + (size_t)NB * LL * DK;       // 8.4MB packed V frags

    avg_k<<<NB * DK, 256, 0, stream>>>(query, avg);
    pi_k<<<NB, 64, 0, stream>>>(weights, avg, pi);
    pack_kv<<<4096, 256, 0, stream>>>(key, value, Kp, Vp);
    zsum_k<<<1024, 256, 0, stream>>>(query, Kp, Zh);
    mos_attn<<<256, 1024, 0, stream>>>(query, Kp, Vp, Zh, pi, out, attn);
}